// Round 6
// baseline (742900.439 us; speedup 1.0000x reference)
//
#include <hip/hip_runtime.h>
#include <hip/hip_bf16.h>

#define T_SEQ 10240

typedef short bf16x8 __attribute__((ext_vector_type(8)));
typedef float f32x4 __attribute__((ext_vector_type(4)));

__device__ __forceinline__ float bf2f(unsigned short u) {
    return __uint_as_float(((unsigned int)u) << 16);
}

// ---------------- mel upsampling: fused repeat(scale) + SAME avg-conv ----------------
__global__ void upsample_kernel(const float* __restrict__ in, float* __restrict__ out,
                                const float* __restrict__ wk,
                                int B, int Tin, int Tout, int shift, int taps)
{
    int idx = blockIdx.x * blockDim.x + threadIdx.x;
    int total = B * Tout * 80;
    if (idx >= total) return;
    int m = idx % 80;
    int r = idx / 80;
    int t = r % Tout;
    int b = r / Tout;
    int s = taps >> 1;
    float acc = 0.f;
    for (int d = -s; d <= s; ++d) {
        int i = t + d;
        if (i >= 0 && i < Tout)
            acc += in[((size_t)b * Tin + (i >> shift)) * 80 + m] * wk[d + s];
    }
    out[idx] = acc;
}

// ---------------- conditioning net: conv0 (VALID, k=5) + BN + relu ----------------
__global__ __launch_bounds__(128) void conv0_kernel(
    const float* __restrict__ mels, const float* __restrict__ w,
    const float* __restrict__ g, const float* __restrict__ b,
    const float* __restrict__ m_, const float* __restrict__ v_,
    float* __restrict__ a)
{
    __shared__ float xin[400];
    int bt = blockIdx.x;              // 0..159
    int bb = bt / 40, t = bt % 40;
    int c = threadIdx.x;
    for (int idx = c; idx < 400; idx += 128)
        xin[idx] = mels[((size_t)bb * 44 + t + idx / 80) * 80 + (idx % 80)];
    __syncthreads();
    float s = 0.f;
    for (int q = 0; q < 400; ++q) s += xin[q] * w[q * 128 + c];
    s = (s - m_[c]) * rsqrtf(v_[c] + 1e-3f) * g[c] + b[c];
    a[bt * 128 + c] = fmaxf(s, 0.f);
}

// ---------------- one residual block ----------------
__global__ __launch_bounds__(128) void resblock_kernel(
    const float* __restrict__ W1, const float* __restrict__ W2,
    const float* __restrict__ g1, const float* __restrict__ b1,
    const float* __restrict__ m1, const float* __restrict__ v1,
    const float* __restrict__ g2, const float* __restrict__ b2,
    const float* __restrict__ m2, const float* __restrict__ v2,
    float* __restrict__ a)
{
    __shared__ float ain[128], y1[128];
    int tok = blockIdx.x;
    int c = threadIdx.x;
    ain[c] = a[tok * 128 + c];
    __syncthreads();
    float s = 0.f;
    #pragma unroll 8
    for (int k = 0; k < 128; ++k) s += ain[k] * W1[k * 128 + c];
    s = (s - m1[c]) * rsqrtf(v1[c] + 1e-3f) * g1[c] + b1[c];
    y1[c] = fmaxf(s, 0.f);
    __syncthreads();
    float s2 = 0.f;
    #pragma unroll 8
    for (int k = 0; k < 128; ++k) s2 += y1[k] * W2[k * 128 + c];
    s2 = (s2 - m2[c]) * rsqrtf(v2[c] + 1e-3f) * g2[c] + b2[c];
    a[tok * 128 + c] = ain[c] + s2;
}

// ---------------- cond out matmul ----------------
__global__ __launch_bounds__(128) void outmat_kernel(
    const float* __restrict__ W, const float* __restrict__ bias,
    const float* __restrict__ a, float* __restrict__ out)
{
    __shared__ float ain[128];
    int tok = blockIdx.x;
    int c = threadIdx.x;
    ain[c] = a[tok * 128 + c];
    __syncthreads();
    float s = 0.f;
    #pragma unroll 8
    for (int k = 0; k < 128; ++k) s += ain[k] * W[k * 128 + c];
    out[tok * 128 + c] = s + bias[c];
}

// ---------------- big fused GEMM (unchanged) ----------------
__device__ __forceinline__ float fetchA(int mode, int row, int k, int K,
    const float* audio, const float* melsup, const float* cond, const float* xA)
{
    if (k >= K) return 0.f;
    int b = row / T_SEQ;
    int t = row - b * T_SEQ;
    if (mode == 0) {
        if (k == 0) return audio[(size_t)b * (T_SEQ + 1) + t];
        if (k < 81) return melsup[((size_t)b * 11264 + 512 + t) * 80 + (k - 1)];
        return cond[((size_t)b * 40 + (t >> 8)) * 128 + (k - 81)];
    }
    if (k < 512) return xA[(size_t)row * 512 + k];
    int co = (mode == 2) ? 32 : (mode == 3) ? 64 : 96;
    return cond[((size_t)b * 40 + (t >> 8)) * 128 + co + (k - 512)];
}

__global__ __launch_bounds__(256) void gemm_big(
    int mode, int N, int K,
    const float* __restrict__ W, const float* __restrict__ bias1,
    const float* __restrict__ bias2,
    const float* __restrict__ audio, const float* __restrict__ melsup,
    const float* __restrict__ cond, const float* __restrict__ xA,
    const float* __restrict__ resid, float* __restrict__ outF,
    __hip_bfloat16* __restrict__ outB)
{
    __shared__ float As[16][68];
    __shared__ float Bs[16][68];
    const int tid = threadIdx.x;
    const int row0 = blockIdx.y * 64;
    const int col0 = blockIdx.x * 64;
    const int tx = tid & 15, ty = tid >> 4;
    float acc[4][4] = {};
    const int nkt = (K + 15) >> 4;
    for (int kt = 0; kt < nkt; ++kt) {
        const int kb = kt << 4;
        #pragma unroll
        for (int l = 0; l < 4; ++l) {
            int k = (tid >> 6) + l * 4;
            int m = tid & 63;
            float bv = 0.f;
            if (kb + k < K) bv = W[(size_t)(kb + k) * N + col0 + m];
            Bs[k][m] = bv;
        }
        if (mode != 0) {
            int m = tid >> 2, kq = tid & 3;
            int row = row0 + m;
            int k = kb + kq * 4;
            if (k + 3 < 512) {
                float4 v = *reinterpret_cast<const float4*>(xA + (size_t)row * 512 + k);
                As[kq * 4 + 0][m] = v.x; As[kq * 4 + 1][m] = v.y;
                As[kq * 4 + 2][m] = v.z; As[kq * 4 + 3][m] = v.w;
            } else {
                #pragma unroll
                for (int i = 0; i < 4; ++i)
                    As[kq * 4 + i][m] = fetchA(mode, row, k + i, K, audio, melsup, cond, xA);
            }
        } else {
            #pragma unroll
            for (int l = 0; l < 4; ++l) {
                int k = (tid >> 6) + l * 4;
                int m = tid & 63;
                As[k][m] = fetchA(0, row0 + m, kb + k, K, audio, melsup, cond, xA);
            }
        }
        __syncthreads();
        #pragma unroll
        for (int k = 0; k < 16; ++k) {
            float a0 = As[k][(ty << 2) + 0], a1 = As[k][(ty << 2) + 1];
            float a2 = As[k][(ty << 2) + 2], a3 = As[k][(ty << 2) + 3];
            float b0 = Bs[k][(tx << 2) + 0], b1 = Bs[k][(tx << 2) + 1];
            float b2 = Bs[k][(tx << 2) + 2], b3 = Bs[k][(tx << 2) + 3];
            acc[0][0] += a0 * b0; acc[0][1] += a0 * b1; acc[0][2] += a0 * b2; acc[0][3] += a0 * b3;
            acc[1][0] += a1 * b0; acc[1][1] += a1 * b1; acc[1][2] += a1 * b2; acc[1][3] += a1 * b3;
            acc[2][0] += a2 * b0; acc[2][1] += a2 * b1; acc[2][2] += a2 * b2; acc[2][3] += a2 * b3;
            acc[3][0] += a3 * b0; acc[3][1] += a3 * b1; acc[3][2] += a3 * b2; acc[3][3] += a3 * b3;
        }
        __syncthreads();
    }
    #pragma unroll
    for (int i = 0; i < 4; ++i) {
        int row = row0 + (ty << 2) + i;
        #pragma unroll
        for (int jt = 0; jt < 4; ++jt) {
            int col = col0 + (tx << 2) + jt;
            float v = acc[i][jt] + bias1[col];
            if (bias2 && col < 1024) v += bias2[col];
            if (mode == 0) {
                outF[(size_t)row * N + col] = v;
            } else if (mode <= 2) {
                outB[(size_t)row * 1536 + col] = __float2bfloat16(v);
            } else {
                v = fmaxf(v, 0.f) + resid[(size_t)row * 512 + col];
                outF[(size_t)row * 512 + col] = v;
            }
        }
    }
}

// ---------------- pack Wh (512,1536) f32 -> per-lane MFMA B-fragments, bf16 ----------------
// frag id g = [s(6)][kt(16)][tid(1024)]; tid = w*64+l.
// s = gate*2 + p ; wave w covers N-tiles jt = w + p*16 ; n = gate*512 + jt*16 + (l&15)
// k = kt*32 + (l>>4)*8 + i   (B[k][n] layout: lane l holds B[(l>>4)*8+i][l&15])
__global__ __launch_bounds__(256) void pack_wh_kernel(const float* __restrict__ Wh,
                                                      unsigned short* __restrict__ out)
{
    int g = blockIdx.x * 256 + threadIdx.x;     // < 98304
    int tid = g & 1023;
    int skt = g >> 10;                          // 0..95
    int kt = skt & 15, s = skt >> 4;
    int w = tid >> 6, l = tid & 63;
    int gg = s >> 1, p = s & 1;
    int n = gg * 512 + (w + p * 16) * 16 + (l & 15);
    int k0 = kt * 32 + (l >> 4) * 8;
    unsigned short* dst = out + (size_t)g * 8;
    #pragma unroll
    for (int i = 0; i < 8; ++i) {
        __hip_bfloat16 hv = __float2bfloat16(Wh[(size_t)(k0 + i) * 1536 + n]);
        dst[i] = *reinterpret_cast<unsigned short*>(&hv);
    }
}

// ---------------- single-workgroup MFMA GRU ----------------
// 1 WG x 1024 threads (16 waves) on one CU. All of Wh (bf16) in registers:
// 96 B-fragments/lane = 384 VGPRs. h in LDS (bf16 copy for MFMA A-operand;
// f32 state in owner-lane registers). One __syncthreads per step; zero
// inter-workgroup traffic. Per step: stage xp/xv[t+1] (issue early, ds_write
// late) || 16 ds_read + 96 MFMA per wave -> acc redistribute via wave-private
// LDS -> 64-lane-parallel gates -> write h_bf[nxt] + xio.
__global__ __launch_bounds__(1024) void gru_mfma(
    const unsigned short* __restrict__ wpack,   // 6*16*1024*8 bf16
    const float* __restrict__ bh,               // (1536); [1024:1536) used
    const __hip_bfloat16* __restrict__ xp,      // (4*T,1536) x@Wx+bx (+bh z/r)
    float* __restrict__ xio,                    // (4*T,512) in: x, out: x+h
    int T)
{
    // LDS: h_bf [buf][kg=64][b=16][8] bf16 (pad batches 4..15 stay zero)
    __shared__ alignas(16) unsigned short h_bf[2][8192];     // 32 KB
    __shared__ alignas(16) unsigned short xp_sh[2][4 * 1536];// 24 KB
    __shared__ alignas(16) float xv_sh[2][4 * 512];          // 16 KB
    __shared__ alignas(16) float acc_sh[16][16][6][4];       // 24 KB (wave-private)

    const int tid = threadIdx.x;
    const int w = tid >> 6;
    const int l = tid & 63;

    // ---- weights into registers (coalesced 16B loads, all static indices) ----
    bf16x8 wf[6][16];
    const bf16x8* wp = reinterpret_cast<const bf16x8*>(wpack);
    #pragma unroll
    for (int s = 0; s < 6; ++s)
        #pragma unroll
        for (int kt = 0; kt < 16; ++kt)
            wf[s][kt] = wp[(s * 16 + kt) * 1024 + tid];

    // gate-lane constants: this lane owns units (q=0/1, b=(l>>4)&3, j16=l&15)
    const int gb = (l >> 4) & 3;
    const int gj16 = l & 15;
    const int gj0 = w * 16 + gj16;              // q=0: jt=w
    const int gj1 = (w + 16) * 16 + gj16;       // q=1: jt=w+16
    const float bhh0 = bh[1024 + gj0];
    const float bhh1 = bh[1024 + gj1];
    float hprev0 = 0.f, hprev1 = 0.f;

    // ---- zero both h_bf buffers (incl. batch pad) ----
    {
        uint4* z = reinterpret_cast<uint4*>(&h_bf[0][0]);
        z[tid] = make_uint4(0, 0, 0, 0);
        z[tid + 1024] = make_uint4(0, 0, 0, 0);
    }
    // ---- stage t=0 ----
    if (tid < 768) {
        int fb = tid * 16;
        int b = fb / 3072, off = fb % 3072;
        uint4 v = *reinterpret_cast<const uint4*>(
            reinterpret_cast<const unsigned short*>(xp) + (size_t)b * T * 1536 + off / 2);
        *reinterpret_cast<uint4*>(&xp_sh[0][fb / 2]) = v;
    } else {
        int st = tid - 768;
        #pragma unroll
        for (int rr = 0; rr < 2; ++rr) {
            int fb = (st * 2 + rr) * 16;
            int b = fb / 2048, idx = (fb % 2048) / 4;
            float4 v = *reinterpret_cast<const float4*>(xio + (size_t)b * T * 512 + idx);
            *reinterpret_cast<float4*>(&xv_sh[0][fb / 4]) = v;
        }
    }
    __syncthreads();

    for (int t = 0; t < T; ++t) {
        const int cur = t & 1, nxt = cur ^ 1;

        // ---- A: issue next-step staging loads (write to LDS later) ----
        uint4 sxp; float4 sxv0, sxv1;
        int xp_dst = 0, xv_dst0 = 0, xv_dst1 = 0;
        const bool do_stage = (t + 1 < T);
        if (do_stage) {
            if (tid < 768) {
                int fb = tid * 16;
                int b = fb / 3072, off = fb % 3072;
                sxp = *reinterpret_cast<const uint4*>(
                    reinterpret_cast<const unsigned short*>(xp) +
                    (size_t)(b * T + t + 1) * 1536 + off / 2);
                xp_dst = fb / 2;
            } else {
                int st = tid - 768;
                int fb0 = (st * 2) * 16, fb1 = (st * 2 + 1) * 16;
                sxv0 = *reinterpret_cast<const float4*>(
                    xio + (size_t)((fb0 / 2048) * T + t + 1) * 512 + (fb0 % 2048) / 4);
                sxv1 = *reinterpret_cast<const float4*>(
                    xio + (size_t)((fb1 / 2048) * T + t + 1) * 512 + (fb1 % 2048) / 4);
                xv_dst0 = fb0 / 4; xv_dst1 = fb1 / 4;
            }
        }

        // ---- B: MFMA h(4x512) x Wh(512x1536), M=4-in-16 ----
        f32x4 acc[6] = {f32x4{0,0,0,0}, f32x4{0,0,0,0}, f32x4{0,0,0,0},
                        f32x4{0,0,0,0}, f32x4{0,0,0,0}, f32x4{0,0,0,0}};
        const unsigned short* hb = &h_bf[cur][0];
        #pragma unroll
        for (int kt = 0; kt < 16; ++kt) {
            const bf16x8 afr = *reinterpret_cast<const bf16x8*>(
                hb + (kt * 4 + (l >> 4)) * 128 + (l & 15) * 8);
            #pragma unroll
            for (int s = 0; s < 6; ++s)
                acc[s] = __builtin_amdgcn_mfma_f32_16x16x32_bf16(afr, wf[s][kt], acc[s], 0, 0, 0);
        }

        // ---- C: redistribute acc (wave-private LDS; same-wave order, no barrier) ----
        if (l < 16) {
            #pragma unroll
            for (int s = 0; s < 6; ++s) {
                acc_sh[w][l][s][0] = acc[s][0];
                acc_sh[w][l][s][1] = acc[s][1];
                acc_sh[w][l][s][2] = acc[s][2];
                acc_sh[w][l][s][3] = acc[s][3];
            }
        }
        #pragma unroll
        for (int q = 0; q < 2; ++q) {
            const int j = q ? gj1 : gj0;
            const float az = acc_sh[w][gj16][0 + q][gb];
            const float ar = acc_sh[w][gj16][2 + q][gb];
            const float ah = acc_sh[w][gj16][4 + q][gb];
            const int xbase = gb * 1536 + j;
            const float xz = bf2f(xp_sh[cur][xbase]);
            const float xr = bf2f(xp_sh[cur][xbase + 512]);
            const float xh = bf2f(xp_sh[cur][xbase + 1024]);
            const float xv = xv_sh[cur][gb * 512 + j];
            const float bhh = q ? bhh1 : bhh0;
            const float hp = q ? hprev1 : hprev0;
            float z = 1.f / (1.f + __expf(-(xz + az)));
            float r = 1.f / (1.f + __expf(-(xr + ar)));
            float e2 = __expf(-2.f * (xh + r * (ah + bhh)));
            float hh = (1.f - e2) / (1.f + e2);
            float hn = z * hp + (1.f - z) * hh;
            if (q) hprev1 = hn; else hprev0 = hn;
            __hip_bfloat16 hb16 = __float2bfloat16(hn);
            h_bf[nxt][(j >> 3) * 128 + gb * 8 + (j & 7)] =
                *reinterpret_cast<unsigned short*>(&hb16);
            xio[(size_t)(gb * T + t) * 512 + j] = xv + hn;
        }

        // ---- D: commit staged t+1 data ----
        if (do_stage) {
            if (tid < 768) {
                *reinterpret_cast<uint4*>(&xp_sh[nxt][xp_dst]) = sxp;
            } else {
                *reinterpret_cast<float4*>(&xv_sh[nxt][xv_dst0]) = sxv0;
                *reinterpret_cast<float4*>(&xv_sh[nxt][xv_dst1]) = sxv1;
            }
        }
        __syncthreads();
    }
}

// ---------------- final projection ----------------
__global__ __launch_bounds__(256) void wp_kernel(
    const float* __restrict__ x, const float* __restrict__ Wp,
    const float* __restrict__ bp, float* __restrict__ out)
{
    int r = threadIdx.x >> 5, c = threadIdx.x & 31;
    size_t row = (size_t)blockIdx.x * 8 + r;
    if (c >= 30) return;
    const float* xr = x + row * 512;
    float acc = 0.f;
    #pragma unroll 8
    for (int k = 0; k < 512; ++k) acc += xr[k] * Wp[k * 30 + c];
    out[row * 30 + c] = acc + bp[c];
}

extern "C" void kernel_launch(void* const* d_in, const int* in_sizes, int n_in,
                              void* d_out, int out_size, void* d_ws, size_t ws_size,
                              hipStream_t stream)
{
    const float* audios = (const float*)d_in[0];
    const float* mels   = (const float*)d_in[1];
    const float* w_mel0 = (const float*)d_in[2];
    const float* w_mel1 = (const float*)d_in[3];
    const float* w_mel2 = (const float*)d_in[4];
    const float* conv0w = (const float*)d_in[5];
    const float* bn0g = (const float*)d_in[6];
    const float* bn0b = (const float*)d_in[7];
    const float* bn0m = (const float*)d_in[8];
    const float* bn0v = (const float*)d_in[9];
    const float* r_w1   = (const float*)d_in[10];
    const float* r_bn1g = (const float*)d_in[11];
    const float* r_bn1b = (const float*)d_in[12];
    const float* r_bn1m = (const float*)d_in[13];
    const float* r_bn1v = (const float*)d_in[14];
    const float* r_w2   = (const float*)d_in[15];
    const float* r_bn2g = (const float*)d_in[16];
    const float* r_bn2b = (const float*)d_in[17];
    const float* r_bn2m = (const float*)d_in[18];
    const float* r_bn2v = (const float*)d_in[19];
    const float* mr_out_w = (const float*)d_in[20];
    const float* mr_out_b = (const float*)d_in[21];
    const float* Wi = (const float*)d_in[22];
    const float* bi = (const float*)d_in[23];
    const float* Wx0 = (const float*)d_in[24];
    const float* Wh0 = (const float*)d_in[25];
    const float* bx0 = (const float*)d_in[26];
    const float* bh0 = (const float*)d_in[27];
    const float* Wx1 = (const float*)d_in[28];
    const float* Wh1 = (const float*)d_in[29];
    const float* bx1 = (const float*)d_in[30];
    const float* bh1 = (const float*)d_in[31];
    const float* Wd0 = (const float*)d_in[32];
    const float* bd0 = (const float*)d_in[33];
    const float* Wd1 = (const float*)d_in[34];
    const float* bd1 = (const float*)d_in[35];
    const float* Wp = (const float*)d_in[36];
    const float* bp = (const float*)d_in[37];

    char* ws = (char*)d_ws;
    size_t off = 0;
    auto alloc = [&](size_t n) { size_t r = off; off += (n + 255) & ~(size_t)255; return r; };
    const size_t M = 4 * (size_t)T_SEQ;                      // 40960
    size_t xp_off = alloc(M * 1536 * 2);                     // bf16 xp; reused as f32 x3
    size_t x_off  = alloc(M * 512 * 4);                      // f32 x
    size_t s1_off = alloc((size_t)4 * 176 * 80 * 4);
    size_t s2_off = alloc((size_t)4 * 1408 * 80 * 4);
    size_t s3_off = alloc((size_t)4 * 11264 * 80 * 4);
    size_t ca_off = alloc((size_t)160 * 128 * 4);
    size_t cf_off = alloc((size_t)160 * 128 * 4);
    size_t wp0_off = alloc((size_t)98304 * 8 * 2);           // packed Wh0 (1.5MB)
    size_t wp1_off = alloc((size_t)98304 * 8 * 2);           // packed Wh1 (1.5MB)

    __hip_bfloat16* xp = (__hip_bfloat16*)(ws + xp_off);
    float* x3   = (float*)(ws + xp_off);
    float* xbuf = (float*)(ws + x_off);
    float* st1  = (float*)(ws + s1_off);
    float* st2  = (float*)(ws + s2_off);
    float* st3  = (float*)(ws + s3_off);
    float* conda = (float*)(ws + ca_off);
    float* condf = (float*)(ws + cf_off);
    unsigned short* wpack0 = (unsigned short*)(ws + wp0_off);
    unsigned short* wpack1 = (unsigned short*)(ws + wp1_off);
    float* outp = (float*)d_out;

    // 0: pack recurrent weights into MFMA fragment order (bf16)
    pack_wh_kernel<<<384, 256, 0, stream>>>(Wh0, wpack0);
    pack_wh_kernel<<<384, 256, 0, stream>>>(Wh1, wpack1);

    // 1-3: mel upsampling
    {
        int tot1 = 4 * 176 * 80;
        upsample_kernel<<<(tot1 + 255) / 256, 256, 0, stream>>>(mels, st1, w_mel0, 4, 44, 176, 2, 9);
        int tot2 = 4 * 1408 * 80;
        upsample_kernel<<<(tot2 + 255) / 256, 256, 0, stream>>>(st1, st2, w_mel1, 4, 176, 1408, 3, 17);
        int tot3 = 4 * 11264 * 80;
        upsample_kernel<<<(tot3 + 255) / 256, 256, 0, stream>>>(st2, st3, w_mel2, 4, 1408, 11264, 3, 17);
    }
    // 4-6: conditioning net
    conv0_kernel<<<160, 128, 0, stream>>>(mels, conv0w, bn0g, bn0b, bn0m, bn0v, conda);
    for (int i = 0; i < 10; ++i) {
        resblock_kernel<<<160, 128, 0, stream>>>(
            r_w1 + (size_t)i * 128 * 128, r_w2 + (size_t)i * 128 * 128,
            r_bn1g + i * 128, r_bn1b + i * 128, r_bn1m + i * 128, r_bn1v + i * 128,
            r_bn2g + i * 128, r_bn2b + i * 128, r_bn2m + i * 128, r_bn2v + i * 128,
            conda);
    }
    outmat_kernel<<<160, 128, 0, stream>>>(mr_out_w, mr_out_b, conda, condf);

    dim3 blk(256);
    // 7: x = concat(audio, mels_up, a0) @ Wi + bi
    gemm_big<<<dim3(8, 640), blk, 0, stream>>>(0, 512, 113, Wi, bi, nullptr,
        audios, st3, condf, nullptr, nullptr, xbuf, nullptr);
    // 8: xp0 = x @ Wx0 + bx0 (+bh0 z/r)
    gemm_big<<<dim3(24, 640), blk, 0, stream>>>(1, 1536, 512, Wx0, bx0, bh0,
        nullptr, nullptr, condf, xbuf, nullptr, nullptr, xp);
    // 9: GRU0 (single workgroup, zero inter-WG sync)
    gru_mfma<<<1, 1024, 0, stream>>>(wpack0, bh0, xp, xbuf, T_SEQ);
    // 10: xp1 = concat(x1, a1) @ Wx1 + bx1 (+bh1 z/r)
    gemm_big<<<dim3(24, 640), blk, 0, stream>>>(2, 1536, 544, Wx1, bx1, bh1,
        nullptr, nullptr, condf, xbuf, nullptr, nullptr, xp);
    // 11: GRU1
    gru_mfma<<<1, 1024, 0, stream>>>(wpack1, bh1, xp, xbuf, T_SEQ);
    // 12: x3 = relu(concat(x2, a2) @ Wd0 + bd0) + x2
    gemm_big<<<dim3(8, 640), blk, 0, stream>>>(3, 512, 544, Wd0, bd0, nullptr,
        nullptr, nullptr, condf, xbuf, xbuf, x3, nullptr);
    // 13: x4 = relu(concat(x3, a3) @ Wd1 + bd1) + x3
    gemm_big<<<dim3(8, 640), blk, 0, stream>>>(4, 512, 544, Wd1, bd1, nullptr,
        nullptr, nullptr, condf, x3, x3, xbuf, nullptr);
    // 14: logits
    wp_kernel<<<5120, 256, 0, stream>>>(xbuf, Wp, bp, outp);
}

// Round 7
// 47589.307 us; speedup vs baseline: 15.6107x; 15.6107x over previous
//
#include <hip/hip_runtime.h>
#include <hip/hip_bf16.h>

#define T_SEQ 10240
#define GRU_W 8

typedef short bf16x8 __attribute__((ext_vector_type(8)));
typedef float f32x4 __attribute__((ext_vector_type(4)));

__device__ __forceinline__ float bf2f(unsigned short u) {
    return __uint_as_float(((unsigned int)u) << 16);
}

// ---------------- mel upsampling: fused repeat(scale) + SAME avg-conv ----------------
__global__ void upsample_kernel(const float* __restrict__ in, float* __restrict__ out,
                                const float* __restrict__ wk,
                                int B, int Tin, int Tout, int shift, int taps)
{
    int idx = blockIdx.x * blockDim.x + threadIdx.x;
    int total = B * Tout * 80;
    if (idx >= total) return;
    int m = idx % 80;
    int r = idx / 80;
    int t = r % Tout;
    int b = r / Tout;
    int s = taps >> 1;
    float acc = 0.f;
    for (int d = -s; d <= s; ++d) {
        int i = t + d;
        if (i >= 0 && i < Tout)
            acc += in[((size_t)b * Tin + (i >> shift)) * 80 + m] * wk[d + s];
    }
    out[idx] = acc;
}

// ---------------- conditioning net: conv0 (VALID, k=5) + BN + relu ----------------
__global__ __launch_bounds__(128) void conv0_kernel(
    const float* __restrict__ mels, const float* __restrict__ w,
    const float* __restrict__ g, const float* __restrict__ b,
    const float* __restrict__ m_, const float* __restrict__ v_,
    float* __restrict__ a)
{
    __shared__ float xin[400];
    int bt = blockIdx.x;              // 0..159
    int bb = bt / 40, t = bt % 40;
    int c = threadIdx.x;
    for (int idx = c; idx < 400; idx += 128)
        xin[idx] = mels[((size_t)bb * 44 + t + idx / 80) * 80 + (idx % 80)];
    __syncthreads();
    float s = 0.f;
    for (int q = 0; q < 400; ++q) s += xin[q] * w[q * 128 + c];
    s = (s - m_[c]) * rsqrtf(v_[c] + 1e-3f) * g[c] + b[c];
    a[bt * 128 + c] = fmaxf(s, 0.f);
}

// ---------------- one residual block ----------------
__global__ __launch_bounds__(128) void resblock_kernel(
    const float* __restrict__ W1, const float* __restrict__ W2,
    const float* __restrict__ g1, const float* __restrict__ b1,
    const float* __restrict__ m1, const float* __restrict__ v1,
    const float* __restrict__ g2, const float* __restrict__ b2,
    const float* __restrict__ m2, const float* __restrict__ v2,
    float* __restrict__ a)
{
    __shared__ float ain[128], y1[128];
    int tok = blockIdx.x;
    int c = threadIdx.x;
    ain[c] = a[tok * 128 + c];
    __syncthreads();
    float s = 0.f;
    #pragma unroll 8
    for (int k = 0; k < 128; ++k) s += ain[k] * W1[k * 128 + c];
    s = (s - m1[c]) * rsqrtf(v1[c] + 1e-3f) * g1[c] + b1[c];
    y1[c] = fmaxf(s, 0.f);
    __syncthreads();
    float s2 = 0.f;
    #pragma unroll 8
    for (int k = 0; k < 128; ++k) s2 += y1[k] * W2[k * 128 + c];
    s2 = (s2 - m2[c]) * rsqrtf(v2[c] + 1e-3f) * g2[c] + b2[c];
    a[tok * 128 + c] = ain[c] + s2;
}

// ---------------- cond out matmul ----------------
__global__ __launch_bounds__(128) void outmat_kernel(
    const float* __restrict__ W, const float* __restrict__ bias,
    const float* __restrict__ a, float* __restrict__ out)
{
    __shared__ float ain[128];
    int tok = blockIdx.x;
    int c = threadIdx.x;
    ain[c] = a[tok * 128 + c];
    __syncthreads();
    float s = 0.f;
    #pragma unroll 8
    for (int k = 0; k < 128; ++k) s += ain[k] * W[k * 128 + c];
    out[tok * 128 + c] = s + bias[c];
}

// ---------------- big fused GEMM (unchanged) ----------------
__device__ __forceinline__ float fetchA(int mode, int row, int k, int K,
    const float* audio, const float* melsup, const float* cond, const float* xA)
{
    if (k >= K) return 0.f;
    int b = row / T_SEQ;
    int t = row - b * T_SEQ;
    if (mode == 0) {
        if (k == 0) return audio[(size_t)b * (T_SEQ + 1) + t];
        if (k < 81) return melsup[((size_t)b * 11264 + 512 + t) * 80 + (k - 1)];
        return cond[((size_t)b * 40 + (t >> 8)) * 128 + (k - 81)];
    }
    if (k < 512) return xA[(size_t)row * 512 + k];
    int co = (mode == 2) ? 32 : (mode == 3) ? 64 : 96;
    return cond[((size_t)b * 40 + (t >> 8)) * 128 + co + (k - 512)];
}

__global__ __launch_bounds__(256) void gemm_big(
    int mode, int N, int K,
    const float* __restrict__ W, const float* __restrict__ bias1,
    const float* __restrict__ bias2,
    const float* __restrict__ audio, const float* __restrict__ melsup,
    const float* __restrict__ cond, const float* __restrict__ xA,
    const float* __restrict__ resid, float* __restrict__ outF,
    __hip_bfloat16* __restrict__ outB)
{
    __shared__ float As[16][68];
    __shared__ float Bs[16][68];
    const int tid = threadIdx.x;
    const int row0 = blockIdx.y * 64;
    const int col0 = blockIdx.x * 64;
    const int tx = tid & 15, ty = tid >> 4;
    float acc[4][4] = {};
    const int nkt = (K + 15) >> 4;
    for (int kt = 0; kt < nkt; ++kt) {
        const int kb = kt << 4;
        #pragma unroll
        for (int l = 0; l < 4; ++l) {
            int k = (tid >> 6) + l * 4;
            int m = tid & 63;
            float bv = 0.f;
            if (kb + k < K) bv = W[(size_t)(kb + k) * N + col0 + m];
            Bs[k][m] = bv;
        }
        if (mode != 0) {
            int m = tid >> 2, kq = tid & 3;
            int row = row0 + m;
            int k = kb + kq * 4;
            if (k + 3 < 512) {
                float4 v = *reinterpret_cast<const float4*>(xA + (size_t)row * 512 + k);
                As[kq * 4 + 0][m] = v.x; As[kq * 4 + 1][m] = v.y;
                As[kq * 4 + 2][m] = v.z; As[kq * 4 + 3][m] = v.w;
            } else {
                #pragma unroll
                for (int i = 0; i < 4; ++i)
                    As[kq * 4 + i][m] = fetchA(mode, row, k + i, K, audio, melsup, cond, xA);
            }
        } else {
            #pragma unroll
            for (int l = 0; l < 4; ++l) {
                int k = (tid >> 6) + l * 4;
                int m = tid & 63;
                As[k][m] = fetchA(0, row0 + m, kb + k, K, audio, melsup, cond, xA);
            }
        }
        __syncthreads();
        #pragma unroll
        for (int k = 0; k < 16; ++k) {
            float a0 = As[k][(ty << 2) + 0], a1 = As[k][(ty << 2) + 1];
            float a2 = As[k][(ty << 2) + 2], a3 = As[k][(ty << 2) + 3];
            float b0 = Bs[k][(tx << 2) + 0], b1 = Bs[k][(tx << 2) + 1];
            float b2 = Bs[k][(tx << 2) + 2], b3 = Bs[k][(tx << 2) + 3];
            acc[0][0] += a0 * b0; acc[0][1] += a0 * b1; acc[0][2] += a0 * b2; acc[0][3] += a0 * b3;
            acc[1][0] += a1 * b0; acc[1][1] += a1 * b1; acc[1][2] += a1 * b2; acc[1][3] += a1 * b3;
            acc[2][0] += a2 * b0; acc[2][1] += a2 * b1; acc[2][2] += a2 * b2; acc[2][3] += a2 * b3;
            acc[3][0] += a3 * b0; acc[3][1] += a3 * b1; acc[3][2] += a3 * b2; acc[3][3] += a3 * b3;
        }
        __syncthreads();
    }
    #pragma unroll
    for (int i = 0; i < 4; ++i) {
        int row = row0 + (ty << 2) + i;
        #pragma unroll
        for (int jt = 0; jt < 4; ++jt) {
            int col = col0 + (tx << 2) + jt;
            float v = acc[i][jt] + bias1[col];
            if (bias2 && col < 1024) v += bias2[col];
            if (mode == 0) {
                outF[(size_t)row * N + col] = v;
            } else if (mode <= 2) {
                outB[(size_t)row * 1536 + col] = __float2bfloat16(v);
            } else {
                v = fmaxf(v, 0.f) + resid[(size_t)row * 512 + col];
                outF[(size_t)row * 512 + col] = v;
            }
        }
    }
}

// ---------------- pack Wh (512,1536) f32 -> 8-WG per-lane MFMA B-fragments, bf16 ----------------
// frag id = (((wg*6 + w)*2 + ntL)*16 + kt)*64 + l ;  nt = 2w+ntL ; g = nt>>2 ; u = nt&3
// n = g*512 + wg*64 + u*16 + (l&15) ; k = kt*32 + (l>>4)*8 + i
__global__ __launch_bounds__(256) void pack_wh_kernel(const float* __restrict__ Wh,
                                                      unsigned short* __restrict__ out)
{
    int gid = blockIdx.x * 256 + threadIdx.x;     // < 98304
    int l = gid & 63;
    int idx = gid >> 6;
    int kt = idx & 15; idx >>= 4;
    int ntL = idx & 1; idx >>= 1;
    int w = idx % 6;
    int wg = idx / 6;
    int nt = 2 * w + ntL;
    int g = nt >> 2, u = nt & 3;
    int n = g * 512 + wg * 64 + u * 16 + (l & 15);
    int k0 = kt * 32 + (l >> 4) * 8;
    unsigned short* dst = out + (size_t)gid * 8;
    #pragma unroll
    for (int i = 0; i < 8; ++i) {
        __hip_bfloat16 hv = __float2bfloat16(Wh[(size_t)(k0 + i) * 1536 + n]);
        dst[i] = *reinterpret_cast<unsigned short*>(&hv);
    }
}

// ---------------- 8-WG MFMA GRU ----------------
// WG wg owns units [wg*64,(wg+1)*64): 192 Wh cols in registers (128 VGPR on
// waves 0-5, 2 Ntiles x 16 Ktiles bf16 fragments). Gates local to owner WG.
// Cross-WG: h published as {tag16|bf16} 4B relaxed agent atomics, ping-pong;
// each thread gang-polls 4 pairs (two independent 8B atomic loads).
// h_sh: [b(16)][512] bf16, 16B-chunk XOR swizzle (chunk ^= b&7).
__global__ __launch_bounds__(512, 2) void gru_mfma8(
    const unsigned short* __restrict__ wpack,   // 8*6*2*16*64*8 bf16
    const float* __restrict__ bh,               // (1536); [1024:1536) used
    const __hip_bfloat16* __restrict__ xp,      // (4*T,1536) x@Wx+bx (+bh z/r)
    float* __restrict__ xio,                    // (4*T,512) in: x, out: x+h
    unsigned int* __restrict__ hpair,           // [2][4][512] u32, memset 0
    int T)
{
    __shared__ alignas(16) unsigned short h_sh[16 * 512];      // 16 KB
    __shared__ alignas(16) unsigned short xp_sh[2][4][3][64];  // 3 KB
    __shared__ alignas(8)  float xv_sh[2][4][64];              // 2 KB
    __shared__ alignas(16) float acc_sh[12][16][4];            // 3 KB

    const int tid = threadIdx.x;
    const int wg = blockIdx.x;
    const int w = tid >> 6;
    const int l = tid & 63;

    // zero h_sh (rows 4-15 stay zero = M-pad)
    {
        uint4* z = reinterpret_cast<uint4*>(h_sh);
        z[tid] = make_uint4(0, 0, 0, 0);
        z[tid + 512] = make_uint4(0, 0, 0, 0);
    }

    // ---- weights into registers (static indices; waves 0-5) ----
    bf16x8 wf[2][16];
    if (w < 6) {
        const bf16x8* wp = reinterpret_cast<const bf16x8*>(wpack);
        const int base = (wg * 6 + w) * 2 * 16 * 64;
        #pragma unroll
        for (int n = 0; n < 2; ++n)
            #pragma unroll
            for (int kt = 0; kt < 16; ++kt)
                wf[n][kt] = wp[base + (n * 16 + kt) * 64 + l];
    }

    float bhh = 0.f, hprev = 0.f;
    if (tid < 256) bhh = bh[1024 + wg * 64 + (tid & 63)];

    // ---- prestage t=0 xp/xv ----
    if (tid < 128) {
        for (int z = tid; z < 192; z += 128) {
            int bg = z >> 4, s = z & 15;
            int b = bg / 3, g = bg % 3;
            unsigned long long v = *reinterpret_cast<const unsigned long long*>(
                reinterpret_cast<const unsigned short*>(xp) +
                (size_t)(b * T) * 1536 + g * 512 + wg * 64 + s * 4);
            *reinterpret_cast<unsigned long long*>(&xp_sh[0][b][g][s * 4]) = v;
        }
        int b = tid >> 5, pr = tid & 31;
        float2 v = *reinterpret_cast<const float2*>(
            xio + (size_t)(b * T) * 512 + wg * 64 + pr * 2);
        *reinterpret_cast<float2*>(&xv_sh[0][b][pr * 2]) = v;
    }
    __syncthreads();

    const unsigned long long* hp64 = reinterpret_cast<const unsigned long long*>(hpair);

    for (int t = 0; t < T; ++t) {
        const int cur = t & 1, nxt = cur ^ 1;

        // ---- poll own 4 pairs: two independent 8B atomic loads ----
        const unsigned long long* src = hp64 + (size_t)cur * 1024 + tid * 2;
        const unsigned tg = (unsigned)t & 0xffffu;
        unsigned long long u0 = __hip_atomic_load(src + 0, __ATOMIC_RELAXED, __HIP_MEMORY_SCOPE_AGENT);
        unsigned long long u1 = __hip_atomic_load(src + 1, __ATOMIC_RELAXED, __HIP_MEMORY_SCOPE_AGENT);
        while ((((unsigned)(u0 >> 16) & 0xffffu) != tg) | ((unsigned)(u0 >> 48) != tg) |
               (((unsigned)(u1 >> 16) & 0xffffu) != tg) | ((unsigned)(u1 >> 48) != tg)) {
            __builtin_amdgcn_s_sleep(1);
            u0 = __hip_atomic_load(src + 0, __ATOMIC_RELAXED, __HIP_MEMORY_SCOPE_AGENT);
            u1 = __hip_atomic_load(src + 1, __ATOMIC_RELAXED, __HIP_MEMORY_SCOPE_AGENT);
        }
        // write 4 bf16 to swizzled h_sh (8B)
        {
            const int pb = tid >> 7;                 // batch 0-3
            const int j0 = (tid * 4) & 511;
            unsigned long long wv =
                (u0 & 0xffffull) | ((u0 >> 32) & 0xffffull) << 16 |
                (u1 & 0xffffull) << 32 | ((u1 >> 32) & 0xffffull) << 48;
            const int chunk = (j0 >> 3) ^ (pb & 7);
            *reinterpret_cast<unsigned long long*>(
                reinterpret_cast<char*>(h_sh) + pb * 1024 + chunk * 16 + (j0 & 7) * 2) = wv;
        }
        __syncthreads();   // h_sh ready

        // ---- stage t+1 xp/xv (waves 6-7) directly into [nxt] ----
        if (w >= 6 && t + 1 < T) {
            int t6 = tid - 384;
            for (int z = t6; z < 192; z += 128) {
                int bg = z >> 4, s = z & 15;
                int b = bg / 3, g = bg % 3;
                unsigned long long v = *reinterpret_cast<const unsigned long long*>(
                    reinterpret_cast<const unsigned short*>(xp) +
                    (size_t)(b * T + t + 1) * 1536 + g * 512 + wg * 64 + s * 4);
                *reinterpret_cast<unsigned long long*>(&xp_sh[nxt][b][g][s * 4]) = v;
            }
            int b = t6 >> 5, pr = t6 & 31;
            float2 v = *reinterpret_cast<const float2*>(
                xio + (size_t)(b * T + t + 1) * 512 + wg * 64 + pr * 2);
            *reinterpret_cast<float2*>(&xv_sh[nxt][b][pr * 2]) = v;
        }

        // ---- MFMA: h(16x512) x Wslice(512x32) per wave (waves 0-5) ----
        if (w < 6) {
            f32x4 acc0 = {0, 0, 0, 0}, acc1 = {0, 0, 0, 0};
            const int rb = l & 15, q = l >> 4;
            #pragma unroll
            for (int kt = 0; kt < 16; ++kt) {
                bf16x8 afr = *reinterpret_cast<const bf16x8*>(
                    reinterpret_cast<const char*>(h_sh) + rb * 1024 +
                    ((((kt * 4 + q) ^ (rb & 7))) << 4));
                acc0 = __builtin_amdgcn_mfma_f32_16x16x32_bf16(afr, wf[0][kt], acc0, 0, 0, 0);
                acc1 = __builtin_amdgcn_mfma_f32_16x16x32_bf16(afr, wf[1][kt], acc1, 0, 0, 0);
            }
            if (l < 16) {
                *reinterpret_cast<f32x4*>(&acc_sh[2 * w][l][0]) = acc0;
                *reinterpret_cast<f32x4*>(&acc_sh[2 * w + 1][l][0]) = acc1;
            }
        }
        __syncthreads();   // acc_sh ready

        // ---- gates: 256 lanes, one (b, unit) each; publish + xio ----
        if (tid < 256) {
            const int b = tid >> 6, jl = tid & 63, j = wg * 64 + jl;
            const int u = jl >> 4, n16 = jl & 15;
            float az = acc_sh[u][n16][b];
            float ar = acc_sh[4 + u][n16][b];
            float ah = acc_sh[8 + u][n16][b];
            float xz = bf2f(xp_sh[cur][b][0][jl]);
            float xr = bf2f(xp_sh[cur][b][1][jl]);
            float xh = bf2f(xp_sh[cur][b][2][jl]);
            float xv = xv_sh[cur][b][jl];
            float z = 1.f / (1.f + __expf(-(xz + az)));
            float r = 1.f / (1.f + __expf(-(xr + ar)));
            float e2 = __expf(-2.f * (xh + r * (ah + bhh)));
            float hh = (1.f - e2) / (1.f + e2);
            float hn = z * hprev + (1.f - z) * hh;
            hprev = hn;
            __hip_bfloat16 hb16 = __float2bfloat16(hn);
            unsigned hv = ((unsigned)((t + 1) & 0xffff) << 16) |
                          (unsigned)*reinterpret_cast<unsigned short*>(&hb16);
            __hip_atomic_store(hpair + (size_t)nxt * 2048 + b * 512 + j, hv,
                               __ATOMIC_RELAXED, __HIP_MEMORY_SCOPE_AGENT);
            xio[(size_t)(b * T + t) * 512 + j] = xv + hn;
        }
        // no end-of-step barrier: sync1(t+1) orders all LDS reuse
    }
}

// ---------------- final projection ----------------
__global__ __launch_bounds__(256) void wp_kernel(
    const float* __restrict__ x, const float* __restrict__ Wp,
    const float* __restrict__ bp, float* __restrict__ out)
{
    int r = threadIdx.x >> 5, c = threadIdx.x & 31;
    size_t row = (size_t)blockIdx.x * 8 + r;
    if (c >= 30) return;
    const float* xr = x + row * 512;
    float acc = 0.f;
    #pragma unroll 8
    for (int k = 0; k < 512; ++k) acc += xr[k] * Wp[k * 30 + c];
    out[row * 30 + c] = acc + bp[c];
}

extern "C" void kernel_launch(void* const* d_in, const int* in_sizes, int n_in,
                              void* d_out, int out_size, void* d_ws, size_t ws_size,
                              hipStream_t stream)
{
    const float* audios = (const float*)d_in[0];
    const float* mels   = (const float*)d_in[1];
    const float* w_mel0 = (const float*)d_in[2];
    const float* w_mel1 = (const float*)d_in[3];
    const float* w_mel2 = (const float*)d_in[4];
    const float* conv0w = (const float*)d_in[5];
    const float* bn0g = (const float*)d_in[6];
    const float* bn0b = (const float*)d_in[7];
    const float* bn0m = (const float*)d_in[8];
    const float* bn0v = (const float*)d_in[9];
    const float* r_w1   = (const float*)d_in[10];
    const float* r_bn1g = (const float*)d_in[11];
    const float* r_bn1b = (const float*)d_in[12];
    const float* r_bn1m = (const float*)d_in[13];
    const float* r_bn1v = (const float*)d_in[14];
    const float* r_w2   = (const float*)d_in[15];
    const float* r_bn2g = (const float*)d_in[16];
    const float* r_bn2b = (const float*)d_in[17];
    const float* r_bn2m = (const float*)d_in[18];
    const float* r_bn2v = (const float*)d_in[19];
    const float* mr_out_w = (const float*)d_in[20];
    const float* mr_out_b = (const float*)d_in[21];
    const float* Wi = (const float*)d_in[22];
    const float* bi = (const float*)d_in[23];
    const float* Wx0 = (const float*)d_in[24];
    const float* Wh0 = (const float*)d_in[25];
    const float* bx0 = (const float*)d_in[26];
    const float* bh0 = (const float*)d_in[27];
    const float* Wx1 = (const float*)d_in[28];
    const float* Wh1 = (const float*)d_in[29];
    const float* bx1 = (const float*)d_in[30];
    const float* bh1 = (const float*)d_in[31];
    const float* Wd0 = (const float*)d_in[32];
    const float* bd0 = (const float*)d_in[33];
    const float* Wd1 = (const float*)d_in[34];
    const float* bd1 = (const float*)d_in[35];
    const float* Wp = (const float*)d_in[36];
    const float* bp = (const float*)d_in[37];

    char* ws = (char*)d_ws;
    size_t off = 0;
    auto alloc = [&](size_t n) { size_t r = off; off += (n + 255) & ~(size_t)255; return r; };
    const size_t M = 4 * (size_t)T_SEQ;                      // 40960
    size_t xp_off = alloc(M * 1536 * 2);                     // bf16 xp; reused as f32 x3
    size_t x_off  = alloc(M * 512 * 4);                      // f32 x
    size_t s1_off = alloc((size_t)4 * 176 * 80 * 4);
    size_t s2_off = alloc((size_t)4 * 1408 * 80 * 4);
    size_t s3_off = alloc((size_t)4 * 11264 * 80 * 4);
    size_t ca_off = alloc((size_t)160 * 128 * 4);
    size_t cf_off = alloc((size_t)160 * 128 * 4);
    size_t wp0_off = alloc((size_t)98304 * 8 * 2);           // packed Wh0 (1.5MB)
    size_t wp1_off = alloc((size_t)98304 * 8 * 2);           // packed Wh1 (1.5MB)
    size_t hp_off  = alloc(2 * 2048 * 4);                    // h pair buffers (16KB)

    __hip_bfloat16* xp = (__hip_bfloat16*)(ws + xp_off);
    float* x3   = (float*)(ws + xp_off);
    float* xbuf = (float*)(ws + x_off);
    float* st1  = (float*)(ws + s1_off);
    float* st2  = (float*)(ws + s2_off);
    float* st3  = (float*)(ws + s3_off);
    float* conda = (float*)(ws + ca_off);
    float* condf = (float*)(ws + cf_off);
    unsigned short* wpack0 = (unsigned short*)(ws + wp0_off);
    unsigned short* wpack1 = (unsigned short*)(ws + wp1_off);
    unsigned int* hpair = (unsigned int*)(ws + hp_off);
    float* outp = (float*)d_out;

    // 0: pack recurrent weights into MFMA fragment order (bf16)
    pack_wh_kernel<<<384, 256, 0, stream>>>(Wh0, wpack0);
    pack_wh_kernel<<<384, 256, 0, stream>>>(Wh1, wpack1);

    // 1-3: mel upsampling
    {
        int tot1 = 4 * 176 * 80;
        upsample_kernel<<<(tot1 + 255) / 256, 256, 0, stream>>>(mels, st1, w_mel0, 4, 44, 176, 2, 9);
        int tot2 = 4 * 1408 * 80;
        upsample_kernel<<<(tot2 + 255) / 256, 256, 0, stream>>>(st1, st2, w_mel1, 4, 176, 1408, 3, 17);
        int tot3 = 4 * 11264 * 80;
        upsample_kernel<<<(tot3 + 255) / 256, 256, 0, stream>>>(st2, st3, w_mel2, 4, 1408, 11264, 3, 17);
    }
    // 4-6: conditioning net
    conv0_kernel<<<160, 128, 0, stream>>>(mels, conv0w, bn0g, bn0b, bn0m, bn0v, conda);
    for (int i = 0; i < 10; ++i) {
        resblock_kernel<<<160, 128, 0, stream>>>(
            r_w1 + (size_t)i * 128 * 128, r_w2 + (size_t)i * 128 * 128,
            r_bn1g + i * 128, r_bn1b + i * 128, r_bn1m + i * 128, r_bn1v + i * 128,
            r_bn2g + i * 128, r_bn2b + i * 128, r_bn2m + i * 128, r_bn2v + i * 128,
            conda);
    }
    outmat_kernel<<<160, 128, 0, stream>>>(mr_out_w, mr_out_b, conda, condf);

    dim3 blk(256);
    // 7: x = concat(audio, mels_up, a0) @ Wi + bi
    gemm_big<<<dim3(8, 640), blk, 0, stream>>>(0, 512, 113, Wi, bi, nullptr,
        audios, st3, condf, nullptr, nullptr, xbuf, nullptr);
    // 8: xp0 = x @ Wx0 + bx0 (+bh0 z/r)
    gemm_big<<<dim3(24, 640), blk, 0, stream>>>(1, 1536, 512, Wx0, bx0, bh0,
        nullptr, nullptr, condf, xbuf, nullptr, nullptr, xp);
    // 9: GRU0 (8 WGs, register-resident weight slices)
    hipMemsetAsync(ws + hp_off, 0, 2 * 2048 * 4, stream);
    gru_mfma8<<<GRU_W, 512, 0, stream>>>(wpack0, bh0, xp, xbuf, hpair, T_SEQ);
    // 10: xp1 = concat(x1, a1) @ Wx1 + bx1 (+bh1 z/r)
    gemm_big<<<dim3(24, 640), blk, 0, stream>>>(2, 1536, 544, Wx1, bx1, bh1,
        nullptr, nullptr, condf, xbuf, nullptr, nullptr, xp);
    // 11: GRU1
    hipMemsetAsync(ws + hp_off, 0, 2 * 2048 * 4, stream);
    gru_mfma8<<<GRU_W, 512, 0, stream>>>(wpack1, bh1, xp, xbuf, hpair, T_SEQ);
    // 12: x3 = relu(concat(x2, a2) @ Wd0 + bd0) + x2
    gemm_big<<<dim3(8, 640), blk, 0, stream>>>(3, 512, 544, Wd0, bd0, nullptr,
        nullptr, nullptr, condf, xbuf, xbuf, x3, nullptr);
    // 13: x4 = relu(concat(x3, a3) @ Wd1 + bd1) + x3
    gemm_big<<<dim3(8, 640), blk, 0, stream>>>(4, 512, 544, Wd1, bd1, nullptr,
        nullptr, nullptr, condf, x3, x3, xbuf, nullptr);
    // 14: logits
    wp_kernel<<<5120, 256, 0, stream>>>(xbuf, Wp, bp, outp);
}